// Round 10
// baseline (192.801 us; speedup 1.0000x reference)
//
#include <hip/hip_runtime.h>
#include <hip/hip_bf16.h>
#include <math.h>

#define BB 4
#define SS 1024
#define DD 1024
#define HH 16
#define DH 64

#define GM 4096          // rows of x-GEMM (B*S)
#define GN 3072          // cols (3 * H * DH)
#define GK 1024          // D

typedef __attribute__((ext_vector_type(4))) float f32x4;
typedef __attribute__((ext_vector_type(8))) short bf16x8;

__device__ __forceinline__ unsigned int pack2bf(float a, float b) {
    __hip_bfloat16 x = __float2bfloat16(a), y = __float2bfloat16(b);
    return (unsigned int)__builtin_bit_cast(unsigned short, x) |
           ((unsigned int)__builtin_bit_cast(unsigned short, y) << 16);
}

__device__ __forceinline__ int swz8(int row) { return (row ^ (row >> 2)) & 7; }

// ---------------------------------------------------------------------------
// Merged prep: [0,4096) convert x->bf16; [4096,4864) build WbT; [4864,4880) WfT
// ---------------------------------------------------------------------------
__global__ __launch_bounds__(256) void prep_kernel(
    const float* __restrict__ x, __hip_bfloat16* __restrict__ xb,
    const float* __restrict__ Wq, const float* __restrict__ Wk,
    const float* __restrict__ Wv, __hip_bfloat16* __restrict__ WbT,
    const float* __restrict__ Wf, unsigned short* __restrict__ WfT)
{
    const int id  = blockIdx.x;
    const int tid = threadIdx.x;
    __shared__ float tile[64][65];

    if (id < 4096) {
        int i = (id * 256 + tid) * 4;
        float4 xv = *(const float4*)(x + i);
        xb[i + 0] = __float2bfloat16(xv.x);
        xb[i + 1] = __float2bfloat16(xv.y);
        xb[i + 2] = __float2bfloat16(xv.z);
        xb[i + 3] = __float2bfloat16(xv.w);
    } else if (id < 4864) {
        const int idx = id - 4096;
        const int d0  = (idx & 15) * 64;
        const int zh  = idx >> 4;
        const int z   = zh >> 4;
        const int h   = zh & 15;
        const float* W = (z == 0) ? Wq : (z == 1) ? Wk : Wv;
        const float* src = W + (size_t)h * DD * DH;
        #pragma unroll
        for (int p = 0; p < 16; p++) {
            int d = p * 4 + (tid >> 6);
            int e = tid & 63;
            tile[d][e] = src[(size_t)(d0 + d) * DH + e];
        }
        __syncthreads();
        #pragma unroll
        for (int p = 0; p < 16; p++) {
            int e = p * 4 + (tid >> 6);
            int d = tid & 63;
            WbT[(size_t)(z * 1024 + h * 64 + e) * GK + d0 + d] =
                __float2bfloat16(tile[d][e]);
        }
    } else {
        const int d0 = (id - 4864) * 64;
        #pragma unroll
        for (int p = 0; p < 16; p++) {
            int e  = p * 4 + (tid >> 6);
            int dd = tid & 63;
            tile[e][dd] = Wf[(size_t)e * DD + d0 + dd];
        }
        __syncthreads();
        #pragma unroll
        for (int p = 0; p < 16; p++) {
            int dd = p * 4 + (tid >> 6);
            int e  = tid & 63;
            __hip_bfloat16 hb = __float2bfloat16(tile[e][dd]);
            WfT[(size_t)(d0 + dd) * DH + e] =
                __builtin_bit_cast(unsigned short, hb);
        }
    }
}

// ---------------------------------------------------------------------------
// bf16 MFMA GEMM: C = A[4096x1024] * Bt[3072][1024]^T.
// A: LDS double-buffer (BK=64), barrier-gated global_load_lds.
// B: register fragments loaded straight from global (L2-resident; grid is
//    (n,m) so same-XCD blocks share n0 -> per-XCD B slice ~768KB), prefetched
//    one K-iter ahead -> compiler pipelines with fine vmcnt, no barrier.
// q/k blocks: swapped-operand MFMA -> C^T -> packed 8B stores [bh][s][e].
// v blocks: normal order -> packed 8B stores to v TRANSPOSED [bh][e][s].
// q pre-scaled by 1/8.
// ---------------------------------------------------------------------------
__global__ __launch_bounds__(256) void gemm_qkv(
    const unsigned short* __restrict__ A,   // xb
    const unsigned short* __restrict__ Bt,  // WbT
    const float* __restrict__ bq, const float* __restrict__ bk,
    const float* __restrict__ bv,
    unsigned short* __restrict__ q, unsigned short* __restrict__ k,
    unsigned short* __restrict__ v)
{
    __shared__ unsigned short As[2][128 * 64];

    const int tid  = threadIdx.x;
    const int wave = tid >> 6;
    const int lane = tid & 63;
    const int n0 = blockIdx.x * 128;     // n-major grid for XCD B-locality
    const int m0 = blockIdx.y * 128;
    const int wy = wave >> 1, wx = wave & 1;
    const bool vblk = (n0 >= 2048);

    const int lrow = lane >> 3;
    const int lcs  = lane & 7;
    const int mrow = lane & 15;
    const int quad = lane >> 4;

    f32x4 acc[4][4];
    #pragma unroll
    for (int i = 0; i < 4; i++)
        #pragma unroll
        for (int j = 0; j < 4; j++)
            acc[i][j] = (f32x4){0.f, 0.f, 0.f, 0.f};

    #define STAGE_A(bufidx, ko)                                                \
        {                                                                      \
            _Pragma("unroll")                                                  \
            for (int c = 0; c < 4; c++) {                                      \
                int region = wave * 4 + c;                                     \
                int row = region * 8 + lrow;                                   \
                int chunk = lcs ^ (row & 7);                                   \
                __builtin_amdgcn_global_load_lds(                              \
                    (const __attribute__((address_space(1))) unsigned int*)    \
                        (A + (size_t)(m0 + row) * GK + (ko) + chunk * 8),      \
                    (__attribute__((address_space(3))) unsigned int*)          \
                        (&As[bufidx][region * 512]), 16, 0, 0);                \
            }                                                                  \
        }

    // B fragment base: col = n0 + wx*64 + nt*16 + mrow, k = ko + ks*32 + quad*8
    const unsigned short* colbase =
        Bt + (size_t)(n0 + wx * 64 + mrow) * GK + quad * 8;

    STAGE_A(0, 0);

    bf16x8 bnxt[8];
    #pragma unroll
    for (int ks = 0; ks < 2; ks++)
        #pragma unroll
        for (int nt = 0; nt < 4; nt++)
            bnxt[ks * 4 + nt] =
                *(const bf16x8*)(colbase + nt * 16 * GK + ks * 32);

    for (int ki = 0; ki < 16; ki++) {
        __syncthreads();                    // A tile ki ready
        if (ki < 15) STAGE_A((ki + 1) & 1, (ki + 1) * 64);

        bf16x8 bcur[8];
        #pragma unroll
        for (int j = 0; j < 8; j++) bcur[j] = bnxt[j];

        if (ki < 15) {
            const int ko = (ki + 1) * 64;
            #pragma unroll
            for (int ks = 0; ks < 2; ks++)
                #pragma unroll
                for (int nt = 0; nt < 4; nt++)
                    bnxt[ks * 4 + nt] =
                        *(const bf16x8*)(colbase + nt * 16 * GK + ko + ks * 32);
        }

        const unsigned short* uA = &As[ki & 1][0];
        #pragma unroll
        for (int ks = 0; ks < 2; ks++) {
            bf16x8 af[4];
            #pragma unroll
            for (int mt = 0; mt < 4; mt++) {
                int row = wy * 64 + mt * 16 + mrow;
                int chunk = (ks * 4 + quad) ^ (row & 7);
                af[mt] = *(const bf16x8*)(uA + row * 64 + chunk * 8);
            }
            if (vblk) {
                #pragma unroll
                for (int mt = 0; mt < 4; mt++)
                    #pragma unroll
                    for (int nt = 0; nt < 4; nt++)
                        acc[mt][nt] = __builtin_amdgcn_mfma_f32_16x16x32_bf16(
                            af[mt], bcur[ks * 4 + nt], acc[mt][nt], 0, 0, 0);
            } else {
                #pragma unroll
                for (int nt = 0; nt < 4; nt++)
                    #pragma unroll
                    for (int mt = 0; mt < 4; mt++)
                        acc[nt][mt] = __builtin_amdgcn_mfma_f32_16x16x32_bf16(
                            bcur[ks * 4 + nt], af[mt], acc[nt][mt], 0, 0, 0);
            }
        }
    }
    #undef STAGE_A

    const int cl = lane & 15;
    const int h  = ((n0 + wx * 64) >> 6) & 15;

    if (!vblk) {
        const int z = n0 >> 10;
        const float* bias = (z == 0) ? bq : bk;
        unsigned short* outp = (z == 0) ? q : k;
        const float sc = (z == 0) ? 0.125f : 1.0f;
        #pragma unroll
        for (int nt = 0; nt < 4; nt++) {
            int ebase = nt * 16 + quad * 4;
            float4 b4 = *(const float4*)(bias + h * 64 + ebase);
            #pragma unroll
            for (int mt = 0; mt < 4; mt++) {
                int m = m0 + wy * 64 + mt * 16 + cl;
                int b = m >> 10, s = m & 1023;
                f32x4 a = acc[nt][mt];
                float v0 = (a[0] + b4.x) * sc;
                float v1 = (a[1] + b4.y) * sc;
                float v2 = (a[2] + b4.z) * sc;
                float v3 = (a[3] + b4.w) * sc;
                uint2 pk = make_uint2(pack2bf(v0, v1), pack2bf(v2, v3));
                *(uint2*)(outp + ((size_t)((b * 16 + h) * 1024 + s)) * 64 + ebase) = pk;
            }
        }
    } else {
        #pragma unroll
        for (int nt = 0; nt < 4; nt++) {
            int e = nt * 16 + cl;
            float bb = bv[h * 64 + e];
            #pragma unroll
            for (int mt = 0; mt < 4; mt++) {
                int rbase = m0 + wy * 64 + mt * 16 + quad * 4;
                int b = rbase >> 10, s = rbase & 1023;
                f32x4 a = acc[mt][nt];
                uint2 pk = make_uint2(pack2bf(a[0] + bb, a[1] + bb),
                                      pack2bf(a[2] + bb, a[3] + bb));
                *(uint2*)(v + ((size_t)((b * 16 + h) * 64 + e)) * 1024 + s) = pk;
            }
        }
    }
}

// ---------------------------------------------------------------------------
// Transposed MFMA flash attention, fixed-max softmax, P kept in registers.
// qi swizzled so the ~4 co-resident blocks per CU get qi offsets {0,4,8,12}.
// Epilogue: accO -> LDS transpose (per-wave slice) -> coalesced atomics.
// ---------------------------------------------------------------------------
__global__ __launch_bounds__(256) void flash_attn(
    const unsigned short* __restrict__ qg, const unsigned short* __restrict__ kg,
    const unsigned short* __restrict__ vtg, float* __restrict__ summed)
{
    __shared__ unsigned short Qs[4096];
    __shared__ unsigned short Ks[2][4096];
    __shared__ unsigned short Vts[2][4096];

    const int x  = blockIdx.x;
    const int y  = blockIdx.y;
    const int qi = (x + (y & 15) + ((y >> 4) << 2)) & 15;   // CU-balance swizzle
    const int q0 = qi * 64;
    const int bh = y;
    const int b  = bh >> 4;
    const int tid  = threadIdx.x;
    const int wave = tid >> 6;
    const int lane = tid & 63;
    const int lrow = lane >> 3;
    const int lcs  = lane & 7;
    const int m16  = lane & 15;
    const int quad = lane >> 4;

    const unsigned short* qb = qg + (size_t)bh * SS * DH;
    const unsigned short* kb = kg + (size_t)bh * SS * DH;
    const unsigned short* vb = vtg + (size_t)bh * SS * DH;  // [e][t] layout

    // stage Q + K tile 0 + V tile 0
    #pragma unroll
    for (int c = 0; c < 2; c++) {
        int region = wave * 2 + c;
        int row = region * 8 + lrow;
        int g = lcs ^ swz8(row);
        __builtin_amdgcn_global_load_lds(
            (const __attribute__((address_space(1))) unsigned int*)
                (qb + (size_t)(q0 + row) * DH + g * 8),
            (__attribute__((address_space(3))) unsigned int*)(Qs + region * 512),
            16, 0, 0);
        __builtin_amdgcn_global_load_lds(
            (const __attribute__((address_space(1))) unsigned int*)
                (kb + (size_t)row * DH + g * 8),
            (__attribute__((address_space(3))) unsigned int*)(&Ks[0][region * 512]),
            16, 0, 0);
        __builtin_amdgcn_global_load_lds(
            (const __attribute__((address_space(1))) unsigned int*)
                (vb + (size_t)row * SS + g * 8),
            (__attribute__((address_space(3))) unsigned int*)(&Vts[0][region * 512]),
            16, 0, 0);
    }

    f32x4 accO[4];
    float lsum = 0.f;
    #pragma unroll
    for (int nt = 0; nt < 4; nt++) accO[nt] = (f32x4){0.f, 0.f, 0.f, 0.f};

    bf16x8 af0, af1;
    const int rloc = wave * 16 + m16;   // this lane's q row (block-local)

    for (int tt = 0; tt <= qi; tt++) {
        __syncthreads();   // vmcnt(0) drain: tile tt (and Q at tt=0) ready

        if (tt == 0) {
            int row = wave * 16 + m16;
            af0 = *(const bf16x8*)(Qs + row * 64 + ((quad ^ swz8(row)) * 8));
            af1 = *(const bf16x8*)(Qs + row * 64 + (((4 + quad) ^ swz8(row)) * 8));
        }

        // prefetch tile tt+1 (flies during compute of tile tt)
        if (tt < qi) {
            const int t1 = (tt + 1) * 64;
            const int bn = (tt + 1) & 1;
            #pragma unroll
            for (int c = 0; c < 2; c++) {
                int region = wave * 2 + c;
                int row = region * 8 + lrow;
                int g = lcs ^ swz8(row);
                __builtin_amdgcn_global_load_lds(
                    (const __attribute__((address_space(1))) unsigned int*)
                        (kb + (size_t)(t1 + row) * DH + g * 8),
                    (__attribute__((address_space(3))) unsigned int*)
                        (&Ks[bn][region * 512]), 16, 0, 0);
                __builtin_amdgcn_global_load_lds(
                    (const __attribute__((address_space(1))) unsigned int*)
                        (vb + (size_t)row * SS + t1 + g * 8),
                    (__attribute__((address_space(3))) unsigned int*)
                        (&Vts[bn][region * 512]), 16, 0, 0);
            }
        }

        const unsigned short* uK = &Ks[tt & 1][0];
        const unsigned short* uV = &Vts[tt & 1][0];

        // S^T: acc[nt] = K(perm) x Q^T; lane holds S[q=m16][t=tau(nt,quad*4+r)]
        f32x4 acc[4];
        #pragma unroll
        for (int nt = 0; nt < 4; nt++) {
            int row = ((nt & 2) << 4) + ((m16 >> 2) << 3) + ((nt & 1) << 2) + (m16 & 3);
            bf16x8 kf0 = *(const bf16x8*)(uK + row * 64 + ((quad ^ swz8(row)) * 8));
            bf16x8 kf1 = *(const bf16x8*)(uK + row * 64 + (((4 + quad) ^ swz8(row)) * 8));
            f32x4 a = (f32x4){0.f, 0.f, 0.f, 0.f};
            a = __builtin_amdgcn_mfma_f32_16x16x32_bf16(kf0, af0, a, 0, 0, 0);
            a = __builtin_amdgcn_mfma_f32_16x16x32_bf16(kf1, af1, a, 0, 0, 0);
            acc[nt] = a;
        }

        // fixed-max softmax; pack P directly into PV B-fragments (in-lane!)
        const bool diag = (tt == qi);
        bf16x8 pf0, pf1;
        #pragma unroll
        for (int nt = 0; nt < 4; nt++) {
            #pragma unroll
            for (int r = 0; r < 4; r++) {
                int tl = ((nt & 2) << 4) + (quad << 3) + ((nt & 1) << 2) + r;
                float s = acc[nt][r];
                if (diag && tl > rloc) s = -1e30f;
                float p = __expf(s);
                lsum += p;
                __hip_bfloat16 hb = __float2bfloat16(p);
                short pb = (short)__builtin_bit_cast(unsigned short, hb);
                int j = ((nt & 1) << 2) + r;
                if (nt < 2) pf0[j] = pb; else pf1[j] = pb;
            }
        }

        // O^T: accO[nt] += V^T(rows e) x P
        #pragma unroll
        for (int nt = 0; nt < 4; nt++) {
            int row = nt * 16 + m16;
            bf16x8 vf0 = *(const bf16x8*)(uV + row * 64 + ((quad ^ swz8(row)) * 8));
            bf16x8 vf1 = *(const bf16x8*)(uV + row * 64 + (((4 + quad) ^ swz8(row)) * 8));
            accO[nt] = __builtin_amdgcn_mfma_f32_16x16x32_bf16(vf0, pf0, accO[nt],
                                                               0, 0, 0);
            accO[nt] = __builtin_amdgcn_mfma_f32_16x16x32_bf16(vf1, pf1, accO[nt],
                                                               0, 0, 0);
        }
    }

    // l-reduce across quads (2 shuffles)
    float l = lsum;
    l += __shfl_xor(l, 16);
    l += __shfl_xor(l, 32);
    const float invl = 1.f / l;

    // epilogue: LDS transpose (per-wave private slice, stride 66) then
    // coalesced atomics: lane = e, 16 rows per wave, 256B/wave/row.
    __syncthreads();   // all waves done reading K/V LDS
    float* buf = (wave < 2) ? (float*)&Ks[0][0] : (float*)&Vts[0][0];
    buf += (wave & 1) * (16 * 66);
    #pragma unroll
    for (int nt = 0; nt < 4; nt++) {
        f32x4 w4 = accO[nt];
        w4 *= invl;
        *(f32x4*)(buf + m16 * 66 + nt * 16 + quad * 4) = w4;
    }
    __asm__ volatile("s_waitcnt lgkmcnt(0)" ::: "memory");  // in-wave slice

    float* dstbase = summed + ((size_t)b * SS + q0 + wave * 16) * DH;
    #pragma unroll
    for (int rr = 0; rr < 16; rr++) {
        float valr = buf[rr * 66 + lane];
        atomicAdd(dstbase + (size_t)rr * DH + lane, valr);
    }
}

// ---------------------------------------------------------------------------
// FF via MFMA: out = gelu_exact(summed[4096x64] @ Wf[64x1024] + bf).
// ---------------------------------------------------------------------------
__global__ __launch_bounds__(256) void ff_mfma(
    const float* __restrict__ summed, const unsigned short* __restrict__ WfT,
    const float* __restrict__ bfb, float* __restrict__ out)
{
    __shared__ unsigned short As[128 * 64];
    __shared__ unsigned short Bs[128 * 64];

    const int tid  = threadIdx.x;
    const int wave = tid >> 6;
    const int lane = tid & 63;
    const int m0 = blockIdx.x * 128;
    const int n0 = blockIdx.y * 128;
    const int wy = wave >> 1, wx = wave & 1;
    const int lrow = lane >> 3;
    const int lcs  = lane & 7;

    // stage B (WfT rows n0..n0+127)
    #pragma unroll
    for (int c = 0; c < 4; c++) {
        int row = (wave * 4 + c) * 8 + lrow;
        int chunk = lcs ^ (row & 7);
        __builtin_amdgcn_global_load_lds(
            (const __attribute__((address_space(1))) unsigned int*)
                (WfT + (size_t)(n0 + row) * DH + chunk * 8),
            (__attribute__((address_space(3))) unsigned int*)
                (Bs + ((wave * 4 + c) * 64) * 8), 16, 0, 0);
    }
    // stage A (summed rows m0..m0+127), fp32 -> bf16, swizzled ds_write_b128
    #pragma unroll
    for (int i = 0; i < 4; i++) {
        int chunkid = tid + i * 256;            // 0..1023
        int row = chunkid >> 3, c = chunkid & 7;
        const float* src = summed + (size_t)(m0 + row) * DH + c * 8;
        float4 a = *(const float4*)src;
        float4 bq = *(const float4*)(src + 4);
        uint4 pk;
        pk.x = pack2bf(a.x, a.y);  pk.y = pack2bf(a.z, a.w);
        pk.z = pack2bf(bq.x, bq.y); pk.w = pack2bf(bq.z, bq.w);
        *(uint4*)(As + row * 64 + ((c ^ (row & 7)) * 8)) = pk;
    }
    __syncthreads();

    f32x4 acc[4][4];
    #pragma unroll
    for (int i = 0; i < 4; i++)
        #pragma unroll
        for (int j = 0; j < 4; j++)
            acc[i][j] = (f32x4){0.f, 0.f, 0.f, 0.f};

    const int mrow = lane & 15;
    const int quad = lane >> 4;
    #pragma unroll
    for (int ks = 0; ks < 2; ks++) {
        bf16x8 af[4], bfr[4];
        #pragma unroll
        for (int mt = 0; mt < 4; mt++) {
            int row = wy * 64 + mt * 16 + mrow;
            int chunk = (ks * 4 + quad) ^ (row & 7);
            af[mt] = *(const bf16x8*)(As + row * 64 + chunk * 8);
        }
        #pragma unroll
        for (int nt = 0; nt < 4; nt++) {
            int row = wx * 64 + nt * 16 + mrow;
            int chunk = (ks * 4 + quad) ^ (row & 7);
            bfr[nt] = *(const bf16x8*)(Bs + row * 64 + chunk * 8);
        }
        #pragma unroll
        for (int mt = 0; mt < 4; mt++)
            #pragma unroll
            for (int nt = 0; nt < 4; nt++)
                acc[mt][nt] = __builtin_amdgcn_mfma_f32_16x16x32_bf16(
                    af[mt], bfr[nt], acc[mt][nt], 0, 0, 0);
    }

    const int cl = lane & 15;
    #pragma unroll
    for (int nt = 0; nt < 4; nt++) {
        int d = n0 + wx * 64 + nt * 16 + cl;
        float bb = bfb[d];
        #pragma unroll
        for (int mt = 0; mt < 4; mt++) {
            int rbase = m0 + wy * 64 + mt * 16 + quad * 4;
            #pragma unroll
            for (int r = 0; r < 4; r++) {
                float vA = acc[mt][nt][r] + bb;
                out[(size_t)(rbase + r) * DD + d] =
                    0.5f * vA * (1.f + erff(vA * 0.70710678118654752f));
            }
        }
    }
}

extern "C" void kernel_launch(void* const* d_in, const int* in_sizes, int n_in,
                              void* d_out, int out_size, void* d_ws, size_t ws_size,
                              hipStream_t stream) {
    const float* x  = (const float*)d_in[0];
    const float* Wq = (const float*)d_in[1];
    const float* bq = (const float*)d_in[2];
    const float* Wk = (const float*)d_in[3];
    const float* bk = (const float*)d_in[4];
    const float* Wv = (const float*)d_in[5];
    const float* bv = (const float*)d_in[6];
    const float* Wf = (const float*)d_in[7];
    const float* bf = (const float*)d_in[8];
    float* out = (float*)d_out;

    const size_t per = (size_t)BB * HH * SS * DH;          // 4,194,304
    unsigned short* q   = (unsigned short*)d_ws;
    unsigned short* k   = q + per;
    unsigned short* v   = k + per;                          // [bh][e][s]
    float* summed       = (float*)(v + per);
    __hip_bfloat16* xb  = (__hip_bfloat16*)(summed + (size_t)BB * SS * DH);
    __hip_bfloat16* WbT = xb + (size_t)BB * SS * DD;        // [3072][1024]
    unsigned short* WfT = (unsigned short*)(WbT + (size_t)GN * GK);  // [1024][64]

    hipMemsetAsync(summed, 0, (size_t)BB * SS * DH * sizeof(float), stream);

    prep_kernel<<<4880, 256, 0, stream>>>(x, (__hip_bfloat16*)xb,
                                          Wq, Wk, Wv, (__hip_bfloat16*)WbT,
                                          Wf, WfT);

    gemm_qkv<<<dim3(GN / 128, GM / 128), 256, 0, stream>>>(
        (const unsigned short*)xb, (const unsigned short*)WbT,
        bq, bk, bv, q, k, v);

    flash_attn<<<dim3(SS / 64, BB * HH), 256, 0, stream>>>(q, k, v, summed);

    ff_mfma<<<dim3(GM / 128, DD / 128), 256, 0, stream>>>(summed, WfT, bf, out);
}

// Round 11
// 168.811 us; speedup vs baseline: 1.1421x; 1.1421x over previous
//
#include <hip/hip_runtime.h>
#include <hip/hip_bf16.h>
#include <math.h>

#define BB 4
#define SS 1024
#define DD 1024
#define HH 16
#define DH 64

#define GM 4096          // rows of x-GEMM (B*S)
#define GN 3072          // cols (3 * H * DH)
#define GK 1024          // D

typedef __attribute__((ext_vector_type(4))) float f32x4;
typedef __attribute__((ext_vector_type(8))) short bf16x8;

__device__ __forceinline__ unsigned int pack2bf(float a, float b) {
    __hip_bfloat16 x = __float2bfloat16(a), y = __float2bfloat16(b);
    return (unsigned int)__builtin_bit_cast(unsigned short, x) |
           ((unsigned int)__builtin_bit_cast(unsigned short, y) << 16);
}

__device__ __forceinline__ int swz8(int row) { return (row ^ (row >> 2)) & 7; }

// ---------------------------------------------------------------------------
// Merged prep: [0,4096) convert x->bf16; [4096,4864) build WbT;
// [4864,4880) WfT; [4880,4896) zero summed (replaces hipMemsetAsync node).
// ---------------------------------------------------------------------------
__global__ __launch_bounds__(256) void prep_kernel(
    const float* __restrict__ x, __hip_bfloat16* __restrict__ xb,
    const float* __restrict__ Wq, const float* __restrict__ Wk,
    const float* __restrict__ Wv, __hip_bfloat16* __restrict__ WbT,
    const float* __restrict__ Wf, unsigned short* __restrict__ WfT,
    float* __restrict__ summed)
{
    const int id  = blockIdx.x;
    const int tid = threadIdx.x;
    __shared__ float tile[64][65];

    if (id < 4096) {
        int i = (id * 256 + tid) * 4;
        float4 xv = *(const float4*)(x + i);
        xb[i + 0] = __float2bfloat16(xv.x);
        xb[i + 1] = __float2bfloat16(xv.y);
        xb[i + 2] = __float2bfloat16(xv.z);
        xb[i + 3] = __float2bfloat16(xv.w);
    } else if (id < 4864) {
        const int idx = id - 4096;
        const int d0  = (idx & 15) * 64;
        const int zh  = idx >> 4;
        const int z   = zh >> 4;
        const int h   = zh & 15;
        const float* W = (z == 0) ? Wq : (z == 1) ? Wk : Wv;
        const float* src = W + (size_t)h * DD * DH;
        #pragma unroll
        for (int p = 0; p < 16; p++) {
            int d = p * 4 + (tid >> 6);
            int e = tid & 63;
            tile[d][e] = src[(size_t)(d0 + d) * DH + e];
        }
        __syncthreads();
        #pragma unroll
        for (int p = 0; p < 16; p++) {
            int e = p * 4 + (tid >> 6);
            int d = tid & 63;
            WbT[(size_t)(z * 1024 + h * 64 + e) * GK + d0 + d] =
                __float2bfloat16(tile[d][e]);
        }
    } else if (id < 4880) {
        const int d0 = (id - 4864) * 64;
        #pragma unroll
        for (int p = 0; p < 16; p++) {
            int e  = p * 4 + (tid >> 6);
            int dd = tid & 63;
            tile[e][dd] = Wf[(size_t)e * DD + d0 + dd];
        }
        __syncthreads();
        #pragma unroll
        for (int p = 0; p < 16; p++) {
            int dd = p * 4 + (tid >> 6);
            int e  = tid & 63;
            __hip_bfloat16 hb = __float2bfloat16(tile[e][dd]);
            WfT[(size_t)(d0 + dd) * DH + e] =
                __builtin_bit_cast(unsigned short, hb);
        }
    } else {
        // zero summed: 262144 floats total, 16 blocks x 16384 floats
        float* dst = summed + (size_t)(id - 4880) * 16384 + tid * 4;
        float4 z4 = make_float4(0.f, 0.f, 0.f, 0.f);
        #pragma unroll
        for (int p = 0; p < 16; p++)
            *(float4*)(dst + p * 1024) = z4;
    }
}

// ---------------------------------------------------------------------------
// bf16 MFMA GEMM (R8 best-known form): C = A[4096x1024] * Bt[3072][1024]^T.
// BK=64, 2-barrier global_load_lds staging, XOR chunk swizzle.
// q/k blocks: swapped-operand MFMA -> C^T -> packed 8B stores [bh][s][e].
// v blocks: normal order -> packed 8B stores to v TRANSPOSED [bh][e][s].
// q pre-scaled by 1/8.
// ---------------------------------------------------------------------------
__global__ __launch_bounds__(256) void gemm_qkv(
    const unsigned short* __restrict__ A,   // xb
    const unsigned short* __restrict__ Bt,  // WbT
    const float* __restrict__ bq, const float* __restrict__ bk,
    const float* __restrict__ bv,
    unsigned short* __restrict__ q, unsigned short* __restrict__ k,
    unsigned short* __restrict__ v)
{
    __shared__ unsigned short As[128 * 64];
    __shared__ unsigned short Bs[128 * 64];

    const int tid  = threadIdx.x;
    const int wave = tid >> 6;
    const int lane = tid & 63;
    const int m0 = blockIdx.x * 128;
    const int n0 = blockIdx.y * 128;
    const int wy = wave >> 1, wx = wave & 1;
    const bool vblk = (n0 >= 2048);

    f32x4 acc[4][4];
    #pragma unroll
    for (int i = 0; i < 4; i++)
        #pragma unroll
        for (int j = 0; j < 4; j++)
            acc[i][j] = (f32x4){0.f, 0.f, 0.f, 0.f};

    const int srow0 = (wave * 4) * 8;
    const int lrow  = lane >> 3;
    const int lcs   = lane & 7;

    for (int ko = 0; ko < GK; ko += 64) {
        __syncthreads();
        #pragma unroll
        for (int c = 0; c < 4; c++) {
            int row = srow0 + c * 8 + lrow;
            int chunk = lcs ^ (row & 7);
            const unsigned short* ga = A + (size_t)(m0 + row) * GK + ko + chunk * 8;
            const unsigned short* gb = Bt + (size_t)(n0 + row) * GK + ko + chunk * 8;
            unsigned short* la = As + ((size_t)(wave * 4 + c) * 64) * 8;
            unsigned short* lb = Bs + ((size_t)(wave * 4 + c) * 64) * 8;
            __builtin_amdgcn_global_load_lds(
                (const __attribute__((address_space(1))) unsigned int*)ga,
                (__attribute__((address_space(3))) unsigned int*)la, 16, 0, 0);
            __builtin_amdgcn_global_load_lds(
                (const __attribute__((address_space(1))) unsigned int*)gb,
                (__attribute__((address_space(3))) unsigned int*)lb, 16, 0, 0);
        }
        __syncthreads();

        const int mrow = lane & 15;
        const int quad = lane >> 4;
        #pragma unroll
        for (int ks = 0; ks < 2; ks++) {
            bf16x8 af[4], bfr[4];
            #pragma unroll
            for (int mt = 0; mt < 4; mt++) {
                int row = wy * 64 + mt * 16 + mrow;
                int chunk = (ks * 4 + quad) ^ (row & 7);
                af[mt] = *(const bf16x8*)(As + row * 64 + chunk * 8);
            }
            #pragma unroll
            for (int nt = 0; nt < 4; nt++) {
                int row = wx * 64 + nt * 16 + mrow;
                int chunk = (ks * 4 + quad) ^ (row & 7);
                bfr[nt] = *(const bf16x8*)(Bs + row * 64 + chunk * 8);
            }
            if (vblk) {
                #pragma unroll
                for (int mt = 0; mt < 4; mt++)
                    #pragma unroll
                    for (int nt = 0; nt < 4; nt++)
                        acc[mt][nt] = __builtin_amdgcn_mfma_f32_16x16x32_bf16(
                            af[mt], bfr[nt], acc[mt][nt], 0, 0, 0);
            } else {
                #pragma unroll
                for (int nt = 0; nt < 4; nt++)
                    #pragma unroll
                    for (int mt = 0; mt < 4; mt++)
                        acc[nt][mt] = __builtin_amdgcn_mfma_f32_16x16x32_bf16(
                            bfr[nt], af[mt], acc[nt][mt], 0, 0, 0);
            }
        }
    }

    const int quad = lane >> 4;
    const int cl   = lane & 15;
    const int h    = ((n0 + wx * 64) >> 6) & 15;

    if (!vblk) {
        const int z = n0 >> 10;
        const float* bias = (z == 0) ? bq : bk;
        unsigned short* outp = (z == 0) ? q : k;
        const float sc = (z == 0) ? 0.125f : 1.0f;
        #pragma unroll
        for (int nt = 0; nt < 4; nt++) {
            int ebase = nt * 16 + quad * 4;
            float4 b4 = *(const float4*)(bias + h * 64 + ebase);
            #pragma unroll
            for (int mt = 0; mt < 4; mt++) {
                int m = m0 + wy * 64 + mt * 16 + cl;
                int b = m >> 10, s = m & 1023;
                f32x4 a = acc[nt][mt];
                float v0 = (a[0] + b4.x) * sc;
                float v1 = (a[1] + b4.y) * sc;
                float v2 = (a[2] + b4.z) * sc;
                float v3 = (a[3] + b4.w) * sc;
                uint2 pk = make_uint2(pack2bf(v0, v1), pack2bf(v2, v3));
                *(uint2*)(outp + ((size_t)((b * 16 + h) * 1024 + s)) * 64 + ebase) = pk;
            }
        }
    } else {
        #pragma unroll
        for (int nt = 0; nt < 4; nt++) {
            int e = nt * 16 + cl;
            float bb = bv[h * 64 + e];
            #pragma unroll
            for (int mt = 0; mt < 4; mt++) {
                int rbase = m0 + wy * 64 + mt * 16 + quad * 4;
                int b = rbase >> 10, s = rbase & 1023;
                f32x4 a = acc[mt][nt];
                uint2 pk = make_uint2(pack2bf(a[0] + bb, a[1] + bb),
                                      pack2bf(a[2] + bb, a[3] + bb));
                *(uint2*)(v + ((size_t)((b * 16 + h) * 64 + e)) * 1024 + s) = pk;
            }
        }
    }
}

// ---------------------------------------------------------------------------
// Transposed MFMA flash attention, fixed-max softmax, P kept in registers.
// qi swizzled so the ~4 co-resident blocks per CU get qi offsets {0,4,8,12}.
// Epilogue: accO -> LDS transpose (per-wave slice) -> coalesced atomics.
// ---------------------------------------------------------------------------
__global__ __launch_bounds__(256) void flash_attn(
    const unsigned short* __restrict__ qg, const unsigned short* __restrict__ kg,
    const unsigned short* __restrict__ vtg, float* __restrict__ summed)
{
    __shared__ unsigned short Qs[4096];
    __shared__ unsigned short Ks[2][4096];
    __shared__ unsigned short Vts[2][4096];

    const int x  = blockIdx.x;
    const int y  = blockIdx.y;
    const int qi = (x + (y & 15) + ((y >> 4) << 2)) & 15;   // CU-balance swizzle
    const int q0 = qi * 64;
    const int bh = y;
    const int b  = bh >> 4;
    const int tid  = threadIdx.x;
    const int wave = tid >> 6;
    const int lane = tid & 63;
    const int lrow = lane >> 3;
    const int lcs  = lane & 7;
    const int m16  = lane & 15;
    const int quad = lane >> 4;

    const unsigned short* qb = qg + (size_t)bh * SS * DH;
    const unsigned short* kb = kg + (size_t)bh * SS * DH;
    const unsigned short* vb = vtg + (size_t)bh * SS * DH;  // [e][t] layout

    // stage Q + K tile 0 + V tile 0
    #pragma unroll
    for (int c = 0; c < 2; c++) {
        int region = wave * 2 + c;
        int row = region * 8 + lrow;
        int g = lcs ^ swz8(row);
        __builtin_amdgcn_global_load_lds(
            (const __attribute__((address_space(1))) unsigned int*)
                (qb + (size_t)(q0 + row) * DH + g * 8),
            (__attribute__((address_space(3))) unsigned int*)(Qs + region * 512),
            16, 0, 0);
        __builtin_amdgcn_global_load_lds(
            (const __attribute__((address_space(1))) unsigned int*)
                (kb + (size_t)row * DH + g * 8),
            (__attribute__((address_space(3))) unsigned int*)(&Ks[0][region * 512]),
            16, 0, 0);
        __builtin_amdgcn_global_load_lds(
            (const __attribute__((address_space(1))) unsigned int*)
                (vb + (size_t)row * SS + g * 8),
            (__attribute__((address_space(3))) unsigned int*)(&Vts[0][region * 512]),
            16, 0, 0);
    }

    f32x4 accO[4];
    float lsum = 0.f;
    #pragma unroll
    for (int nt = 0; nt < 4; nt++) accO[nt] = (f32x4){0.f, 0.f, 0.f, 0.f};

    bf16x8 af0, af1;
    const int rloc = wave * 16 + m16;   // this lane's q row (block-local)

    for (int tt = 0; tt <= qi; tt++) {
        __syncthreads();   // vmcnt(0) drain: tile tt (and Q at tt=0) ready

        if (tt == 0) {
            int row = wave * 16 + m16;
            af0 = *(const bf16x8*)(Qs + row * 64 + ((quad ^ swz8(row)) * 8));
            af1 = *(const bf16x8*)(Qs + row * 64 + (((4 + quad) ^ swz8(row)) * 8));
        }

        // prefetch tile tt+1 (flies during compute of tile tt)
        if (tt < qi) {
            const int t1 = (tt + 1) * 64;
            const int bn = (tt + 1) & 1;
            #pragma unroll
            for (int c = 0; c < 2; c++) {
                int region = wave * 2 + c;
                int row = region * 8 + lrow;
                int g = lcs ^ swz8(row);
                __builtin_amdgcn_global_load_lds(
                    (const __attribute__((address_space(1))) unsigned int*)
                        (kb + (size_t)(t1 + row) * DH + g * 8),
                    (__attribute__((address_space(3))) unsigned int*)
                        (&Ks[bn][region * 512]), 16, 0, 0);
                __builtin_amdgcn_global_load_lds(
                    (const __attribute__((address_space(1))) unsigned int*)
                        (vb + (size_t)row * SS + t1 + g * 8),
                    (__attribute__((address_space(3))) unsigned int*)
                        (&Vts[bn][region * 512]), 16, 0, 0);
            }
        }

        const unsigned short* uK = &Ks[tt & 1][0];
        const unsigned short* uV = &Vts[tt & 1][0];

        // S^T: acc[nt] = K(perm) x Q^T; lane holds S[q=m16][t=tau(nt,quad*4+r)]
        f32x4 acc[4];
        #pragma unroll
        for (int nt = 0; nt < 4; nt++) {
            int row = ((nt & 2) << 4) + ((m16 >> 2) << 3) + ((nt & 1) << 2) + (m16 & 3);
            bf16x8 kf0 = *(const bf16x8*)(uK + row * 64 + ((quad ^ swz8(row)) * 8));
            bf16x8 kf1 = *(const bf16x8*)(uK + row * 64 + (((4 + quad) ^ swz8(row)) * 8));
            f32x4 a = (f32x4){0.f, 0.f, 0.f, 0.f};
            a = __builtin_amdgcn_mfma_f32_16x16x32_bf16(kf0, af0, a, 0, 0, 0);
            a = __builtin_amdgcn_mfma_f32_16x16x32_bf16(kf1, af1, a, 0, 0, 0);
            acc[nt] = a;
        }

        // fixed-max softmax; pack P directly into PV B-fragments (in-lane!)
        const bool diag = (tt == qi);
        bf16x8 pf0, pf1;
        #pragma unroll
        for (int nt = 0; nt < 4; nt++) {
            #pragma unroll
            for (int r = 0; r < 4; r++) {
                int tl = ((nt & 2) << 4) + (quad << 3) + ((nt & 1) << 2) + r;
                float s = acc[nt][r];
                if (diag && tl > rloc) s = -1e30f;
                float p = __expf(s);
                lsum += p;
                __hip_bfloat16 hb = __float2bfloat16(p);
                short pb = (short)__builtin_bit_cast(unsigned short, hb);
                int j = ((nt & 1) << 2) + r;
                if (nt < 2) pf0[j] = pb; else pf1[j] = pb;
            }
        }

        // O^T: accO[nt] += V^T(rows e) x P
        #pragma unroll
        for (int nt = 0; nt < 4; nt++) {
            int row = nt * 16 + m16;
            bf16x8 vf0 = *(const bf16x8*)(uV + row * 64 + ((quad ^ swz8(row)) * 8));
            bf16x8 vf1 = *(const bf16x8*)(uV + row * 64 + (((4 + quad) ^ swz8(row)) * 8));
            accO[nt] = __builtin_amdgcn_mfma_f32_16x16x32_bf16(vf0, pf0, accO[nt],
                                                               0, 0, 0);
            accO[nt] = __builtin_amdgcn_mfma_f32_16x16x32_bf16(vf1, pf1, accO[nt],
                                                               0, 0, 0);
        }
    }

    // l-reduce across quads (2 shuffles)
    float l = lsum;
    l += __shfl_xor(l, 16);
    l += __shfl_xor(l, 32);
    const float invl = 1.f / l;

    // epilogue: LDS transpose (per-wave private slice, stride 66) then
    // coalesced atomics: lane = e, 16 rows per wave, 256B/wave/row.
    __syncthreads();   // all waves done reading K/V LDS
    float* buf = (wave < 2) ? (float*)&Ks[0][0] : (float*)&Vts[0][0];
    buf += (wave & 1) * (16 * 66);
    #pragma unroll
    for (int nt = 0; nt < 4; nt++) {
        f32x4 w4 = accO[nt];
        w4 *= invl;
        *(f32x4*)(buf + m16 * 66 + nt * 16 + quad * 4) = w4;
    }
    __asm__ volatile("s_waitcnt lgkmcnt(0)" ::: "memory");  // in-wave slice

    float* dstbase = summed + ((size_t)b * SS + q0 + wave * 16) * DH;
    #pragma unroll
    for (int rr = 0; rr < 16; rr++) {
        float valr = buf[rr * 66 + lane];
        atomicAdd(dstbase + (size_t)rr * DH + lane, valr);
    }
}

// ---------------------------------------------------------------------------
// FF via MFMA: out = gelu_exact(summed[4096x64] @ Wf[64x1024] + bf).
// ---------------------------------------------------------------------------
__global__ __launch_bounds__(256) void ff_mfma(
    const float* __restrict__ summed, const unsigned short* __restrict__ WfT,
    const float* __restrict__ bfb, float* __restrict__ out)
{
    __shared__ unsigned short As[128 * 64];
    __shared__ unsigned short Bs[128 * 64];

    const int tid  = threadIdx.x;
    const int wave = tid >> 6;
    const int lane = tid & 63;
    const int m0 = blockIdx.x * 128;
    const int n0 = blockIdx.y * 128;
    const int wy = wave >> 1, wx = wave & 1;
    const int lrow = lane >> 3;
    const int lcs  = lane & 7;

    // stage B (WfT rows n0..n0+127)
    #pragma unroll
    for (int c = 0; c < 4; c++) {
        int row = (wave * 4 + c) * 8 + lrow;
        int chunk = lcs ^ (row & 7);
        __builtin_amdgcn_global_load_lds(
            (const __attribute__((address_space(1))) unsigned int*)
                (WfT + (size_t)(n0 + row) * DH + chunk * 8),
            (__attribute__((address_space(3))) unsigned int*)
                (Bs + ((wave * 4 + c) * 64) * 8), 16, 0, 0);
    }
    // stage A (summed rows m0..m0+127), fp32 -> bf16, swizzled ds_write_b128
    #pragma unroll
    for (int i = 0; i < 4; i++) {
        int chunkid = tid + i * 256;            // 0..1023
        int row = chunkid >> 3, c = chunkid & 7;
        const float* src = summed + (size_t)(m0 + row) * DH + c * 8;
        float4 a = *(const float4*)src;
        float4 bq = *(const float4*)(src + 4);
        uint4 pk;
        pk.x = pack2bf(a.x, a.y);  pk.y = pack2bf(a.z, a.w);
        pk.z = pack2bf(bq.x, bq.y); pk.w = pack2bf(bq.z, bq.w);
        *(uint4*)(As + row * 64 + ((c ^ (row & 7)) * 8)) = pk;
    }
    __syncthreads();

    f32x4 acc[4][4];
    #pragma unroll
    for (int i = 0; i < 4; i++)
        #pragma unroll
        for (int j = 0; j < 4; j++)
            acc[i][j] = (f32x4){0.f, 0.f, 0.f, 0.f};

    const int mrow = lane & 15;
    const int quad = lane >> 4;
    #pragma unroll
    for (int ks = 0; ks < 2; ks++) {
        bf16x8 af[4], bfr[4];
        #pragma unroll
        for (int mt = 0; mt < 4; mt++) {
            int row = wy * 64 + mt * 16 + mrow;
            int chunk = (ks * 4 + quad) ^ (row & 7);
            af[mt] = *(const bf16x8*)(As + row * 64 + chunk * 8);
        }
        #pragma unroll
        for (int nt = 0; nt < 4; nt++) {
            int row = wx * 64 + nt * 16 + mrow;
            int chunk = (ks * 4 + quad) ^ (row & 7);
            bfr[nt] = *(const bf16x8*)(Bs + row * 64 + chunk * 8);
        }
        #pragma unroll
        for (int mt = 0; mt < 4; mt++)
            #pragma unroll
            for (int nt = 0; nt < 4; nt++)
                acc[mt][nt] = __builtin_amdgcn_mfma_f32_16x16x32_bf16(
                    af[mt], bfr[nt], acc[mt][nt], 0, 0, 0);
    }

    const int cl = lane & 15;
    #pragma unroll
    for (int nt = 0; nt < 4; nt++) {
        int d = n0 + wx * 64 + nt * 16 + cl;
        float bb = bfb[d];
        #pragma unroll
        for (int mt = 0; mt < 4; mt++) {
            int rbase = m0 + wy * 64 + mt * 16 + quad * 4;
            #pragma unroll
            for (int r = 0; r < 4; r++) {
                float vA = acc[mt][nt][r] + bb;
                out[(size_t)(rbase + r) * DD + d] =
                    0.5f * vA * (1.f + erff(vA * 0.70710678118654752f));
            }
        }
    }
}

extern "C" void kernel_launch(void* const* d_in, const int* in_sizes, int n_in,
                              void* d_out, int out_size, void* d_ws, size_t ws_size,
                              hipStream_t stream) {
    const float* x  = (const float*)d_in[0];
    const float* Wq = (const float*)d_in[1];
    const float* bq = (const float*)d_in[2];
    const float* Wk = (const float*)d_in[3];
    const float* bk = (const float*)d_in[4];
    const float* Wv = (const float*)d_in[5];
    const float* bv = (const float*)d_in[6];
    const float* Wf = (const float*)d_in[7];
    const float* bf = (const float*)d_in[8];
    float* out = (float*)d_out;

    const size_t per = (size_t)BB * HH * SS * DH;          // 4,194,304
    unsigned short* q   = (unsigned short*)d_ws;
    unsigned short* k   = q + per;
    unsigned short* v   = k + per;                          // [bh][e][s]
    float* summed       = (float*)(v + per);
    __hip_bfloat16* xb  = (__hip_bfloat16*)(summed + (size_t)BB * SS * DH);
    __hip_bfloat16* WbT = xb + (size_t)BB * SS * DD;        // [3072][1024]
    unsigned short* WfT = (unsigned short*)(WbT + (size_t)GN * GK);  // [1024][64]

    prep_kernel<<<4896, 256, 0, stream>>>(x, (__hip_bfloat16*)xb,
                                          Wq, Wk, Wv, (__hip_bfloat16*)WbT,
                                          Wf, WfT, summed);

    gemm_qkv<<<dim3(GM / 128, GN / 128), 256, 0, stream>>>(
        (const unsigned short*)xb, (const unsigned short*)WbT,
        bq, bk, bv, q, k, v);

    flash_attn<<<dim3(SS / 64, BB * HH), 256, 0, stream>>>(q, k, v, summed);

    ff_mfma<<<dim3(GM / 128, DD / 128), 256, 0, stream>>>(summed, WfT, bf, out);
}